// Round 1
// baseline (488.992 us; speedup 1.0000x reference)
//
#include <hip/hip_runtime.h>
#include <hip/hip_bf16.h>

#define NH 4
#define HDIM 64
#define HD 256      // NH*HDIM
#define BATCH 8
#define NNODE 2048
#define FDIM 256
#define MROWS (BATCH*NNODE)   // 16384

// ---------------------------------------------------------------------------
// GEMM1: Wh = features @ W   (M=16384, K=256, N=256)
// BM=64, BN=64 (== one head), BK=16, 256 threads, 4x4 micro-tile.
// Epilogue also produces e[row][head] = sum_d Wh[row, head*64+d]^2
// ---------------------------------------------------------------------------
__global__ __launch_bounds__(256) void gemm1_kernel(
    const float* __restrict__ A,   // [M, FDIM]
    const float* __restrict__ W,   // [FDIM, HD]
    float* __restrict__ Wh,        // [M, HD]
    float* __restrict__ e)         // [M, NH]
{
    __shared__ float As[16][64];
    __shared__ float Bs[16][64];

    const int tid  = threadIdx.x;
    const int bm   = blockIdx.x;       // 0..255
    const int head = blockIdx.y;       // 0..3
    const int row0 = bm * 64;
    const int col0 = head * 64;

    const int tr = tid >> 4;           // 0..15
    const int tc = tid & 15;           // 0..15

    // staging indices
    const int ar = tid >> 2;           // 0..63 (row in tile)
    const int ak = (tid & 3) * 4;      // 0,4,8,12
    const int bk = tid >> 4;           // 0..15
    const int bc = (tid & 15) * 4;     // 0..60

    float acc[4][4] = {};

    for (int k0 = 0; k0 < FDIM; k0 += 16) {
        float4 av = *(const float4*)&A[(size_t)(row0 + ar) * FDIM + k0 + ak];
        float4 bv = *(const float4*)&W[(size_t)(k0 + bk) * HD + col0 + bc];
        __syncthreads();   // previous iteration's reads complete
        As[ak + 0][ar] = av.x;
        As[ak + 1][ar] = av.y;
        As[ak + 2][ar] = av.z;
        As[ak + 3][ar] = av.w;
        *(float4*)&Bs[bk][bc] = bv;
        __syncthreads();
        #pragma unroll
        for (int kk = 0; kk < 16; ++kk) {
            float4 a = *(const float4*)&As[kk][tr * 4];
            float4 b = *(const float4*)&Bs[kk][tc * 4];
            acc[0][0] += a.x * b.x; acc[0][1] += a.x * b.y; acc[0][2] += a.x * b.z; acc[0][3] += a.x * b.w;
            acc[1][0] += a.y * b.x; acc[1][1] += a.y * b.y; acc[1][2] += a.y * b.z; acc[1][3] += a.y * b.w;
            acc[2][0] += a.z * b.x; acc[2][1] += a.z * b.y; acc[2][2] += a.z * b.z; acc[2][3] += a.z * b.w;
            acc[3][0] += a.w * b.x; acc[3][1] += a.w * b.y; acc[3][2] += a.w * b.z; acc[3][3] += a.w * b.w;
        }
    }

    // write Wh
    #pragma unroll
    for (int i = 0; i < 4; ++i) {
        const int r = row0 + tr * 4 + i;
        float4 v = make_float4(acc[i][0], acc[i][1], acc[i][2], acc[i][3]);
        *(float4*)&Wh[(size_t)r * HD + col0 + tc * 4] = v;
    }

    // e reduction: partial sum of squares over this thread's 4 columns, per row
    __syncthreads();                   // done reading As/Bs
    float* red = &As[0][0];            // reuse as [64][16]
    #pragma unroll
    for (int i = 0; i < 4; ++i) {
        float p = acc[i][0] * acc[i][0] + acc[i][1] * acc[i][1]
                + acc[i][2] * acc[i][2] + acc[i][3] * acc[i][3];
        red[(tr * 4 + i) * 16 + tc] = p;
    }
    __syncthreads();
    if (tid < 64) {
        float s = 0.f;
        #pragma unroll
        for (int t = 0; t < 16; ++t) s += red[tid * 16 + t];
        e[(size_t)(row0 + tid) * NH + head] = s;
    }
}

// ---------------------------------------------------------------------------
// softmax over nodes per (batch, head), then mean over heads -> att[b, n]
// one block per batch
// ---------------------------------------------------------------------------
__global__ __launch_bounds__(256) void softmax_kernel(
    const float* __restrict__ e,   // [B*N, NH]
    float* __restrict__ att)       // [B*N]
{
    __shared__ float red[256];
    const int b = blockIdx.x;
    const int tid = threadIdx.x;
    const size_t base = (size_t)b * NNODE;

    float m[NH], s[NH];
    for (int h = 0; h < NH; ++h) {
        float mx = -1e30f;
        for (int n = tid; n < NNODE; n += 256)
            mx = fmaxf(mx, e[(base + n) * NH + h]);
        red[tid] = mx;
        __syncthreads();
        for (int o = 128; o > 0; o >>= 1) {
            if (tid < o) red[tid] = fmaxf(red[tid], red[tid + o]);
            __syncthreads();
        }
        mx = red[0];
        __syncthreads();

        float sum = 0.f;
        for (int n = tid; n < NNODE; n += 256)
            sum += expf(e[(base + n) * NH + h] - mx);
        red[tid] = sum;
        __syncthreads();
        for (int o = 128; o > 0; o >>= 1) {
            if (tid < o) red[tid] += red[tid + o];
            __syncthreads();
        }
        m[h] = mx;
        s[h] = red[0];
        __syncthreads();
    }

    for (int n = tid; n < NNODE; n += 256) {
        float a = 0.f;
        #pragma unroll
        for (int h = 0; h < NH; ++h)
            a += expf(e[(base + n) * NH + h] - m[h]) / s[h];
        att[base + n] = a * 0.25f;
    }
}

// ---------------------------------------------------------------------------
// GEMM2: out[b] = relu(att[b,:,None] * (adj[b] @ Wh[b]) + bias)
// per batch: M=2048, K=2048, N=256.  BM=64, BN=64, BK=16.
// ---------------------------------------------------------------------------
__global__ __launch_bounds__(256) void gemm2_kernel(
    const float* __restrict__ adj,   // [B, N, N]
    const float* __restrict__ Wh,    // [B*N, HD]
    const float* __restrict__ att,   // [B*N]
    const float* __restrict__ bias,  // [HD]
    float* __restrict__ out)         // [B*N, HD]
{
    __shared__ float As[16][64];
    __shared__ float Bs[16][64];

    const int tid = threadIdx.x;
    const int bm  = blockIdx.x;       // 0..31
    const int bn  = blockIdx.y;       // 0..3
    const int b   = blockIdx.z;       // 0..7
    const int row0 = bm * 64;
    const int col0 = bn * 64;

    const float* Ab = adj + (size_t)b * NNODE * NNODE;
    const float* Bb = Wh  + (size_t)b * NNODE * HD;

    const int tr = tid >> 4;
    const int tc = tid & 15;
    const int ar = tid >> 2;
    const int ak = (tid & 3) * 4;
    const int bk = tid >> 4;
    const int bc = (tid & 15) * 4;

    float acc[4][4] = {};

    for (int k0 = 0; k0 < NNODE; k0 += 16) {
        float4 av = *(const float4*)&Ab[(size_t)(row0 + ar) * NNODE + k0 + ak];
        float4 bv = *(const float4*)&Bb[(size_t)(k0 + bk) * HD + col0 + bc];
        __syncthreads();
        As[ak + 0][ar] = av.x;
        As[ak + 1][ar] = av.y;
        As[ak + 2][ar] = av.z;
        As[ak + 3][ar] = av.w;
        *(float4*)&Bs[bk][bc] = bv;
        __syncthreads();
        #pragma unroll
        for (int kk = 0; kk < 16; ++kk) {
            float4 a = *(const float4*)&As[kk][tr * 4];
            float4 b4 = *(const float4*)&Bs[kk][tc * 4];
            acc[0][0] += a.x * b4.x; acc[0][1] += a.x * b4.y; acc[0][2] += a.x * b4.z; acc[0][3] += a.x * b4.w;
            acc[1][0] += a.y * b4.x; acc[1][1] += a.y * b4.y; acc[1][2] += a.y * b4.z; acc[1][3] += a.y * b4.w;
            acc[2][0] += a.z * b4.x; acc[2][1] += a.z * b4.y; acc[2][2] += a.z * b4.z; acc[2][3] += a.z * b4.w;
            acc[3][0] += a.w * b4.x; acc[3][1] += a.w * b4.y; acc[3][2] += a.w * b4.z; acc[3][3] += a.w * b4.w;
        }
    }

    const float4 bv = *(const float4*)&bias[col0 + tc * 4];
    #pragma unroll
    for (int i = 0; i < 4; ++i) {
        const int r = row0 + tr * 4 + i;
        const float a = att[(size_t)b * NNODE + r];
        float4 v;
        v.x = fmaxf(a * acc[i][0] + bv.x, 0.f);
        v.y = fmaxf(a * acc[i][1] + bv.y, 0.f);
        v.z = fmaxf(a * acc[i][2] + bv.z, 0.f);
        v.w = fmaxf(a * acc[i][3] + bv.w, 0.f);
        *(float4*)&out[((size_t)b * NNODE + r) * HD + col0 + tc * 4] = v;
    }
}

extern "C" void kernel_launch(void* const* d_in, const int* in_sizes, int n_in,
                              void* d_out, int out_size, void* d_ws, size_t ws_size,
                              hipStream_t stream) {
    const float* features = (const float*)d_in[0];   // [8,2048,256]
    const float* adj      = (const float*)d_in[1];   // [8,2048,2048]
    const float* W        = (const float*)d_in[2];   // [256,256]
    const float* bias     = (const float*)d_in[3];   // [256]
    float* out = (float*)d_out;

    float* ws  = (float*)d_ws;
    float* Wh  = ws;                               // 16384*256 floats
    float* e   = Wh + (size_t)MROWS * HD;          // 16384*4
    float* att = e + (size_t)MROWS * NH;           // 16384

    gemm1_kernel<<<dim3(MROWS / 64, NH), 256, 0, stream>>>(features, W, Wh, e);
    softmax_kernel<<<BATCH, 256, 0, stream>>>(e, att);
    gemm2_kernel<<<dim3(NNODE / 64, HD / 64, BATCH), 256, 0, stream>>>(adj, Wh, att, bias, out);
}

// Round 3
// 324.266 us; speedup vs baseline: 1.5080x; 1.5080x over previous
//
#include <hip/hip_runtime.h>
#include <hip/hip_bf16.h>

#define BATCH 8
#define NNODE 2048
#define FDIM 256
#define HD 256
#define NH 4
#define MROWS (BATCH*NNODE)
#define BK 64

typedef float f32x4 __attribute__((ext_vector_type(4)));
typedef short s16x8 __attribute__((ext_vector_type(8)));

__device__ __forceinline__ unsigned short f2bf(float f) {
    unsigned u = __builtin_bit_cast(unsigned, f);
    u += 0x7fffu + ((u >> 16) & 1u);
    return (unsigned short)(u >> 16);
}
__device__ __forceinline__ float bf2f(unsigned short h) {
    return __builtin_bit_cast(float, (unsigned)h << 16);
}

#define MFMA __builtin_amdgcn_mfma_f32_16x16x32_bf16

// ---------------------------------------------------------------------------
// Shared 128x128xBK split-bf16 MFMA main loop.
// A: fp32 [.][astride], converted to hi/lo bf16 on the fly.
// B: pre-split bf16 hi/lo, stored [col][k] (k contiguous), row stride bstride.
// LDS tiles are [row][k] with 16-B-granule XOR swizzle (g ^= row&7) on 128-B rows.
// acc = A*B via 3 products: ah*bh + ah*bl + al*bh.
// ---------------------------------------------------------------------------
__device__ __forceinline__ void mfma_mainloop(
    const float* __restrict__ Ab, int astride,
    const unsigned short* __restrict__ Bph,
    const unsigned short* __restrict__ Bpl, int bstride,
    int nt, unsigned short (&lds)[2][4][128 * BK],
    int tid, int lane, int wr, int wc,
    f32x4 (&acc)[4][4])
{
    f32x4 ar[8];
    uint4 brh[4], brl[4];

    // ---- issue loads for tile 0
    #pragma unroll
    for (int i = 0; i < 4; ++i) {
        const int g = tid + 256 * i, r = g >> 3, gk = g & 7;
        ar[2*i]   = *(const f32x4*)&Ab[(size_t)r * astride + gk * 8];
        ar[2*i+1] = *(const f32x4*)&Ab[(size_t)r * astride + gk * 8 + 4];
        brh[i] = *(const uint4*)&Bph[(size_t)r * bstride + gk * 8];
        brl[i] = *(const uint4*)&Bpl[(size_t)r * bstride + gk * 8];
    }

    #define STAGE_WRITE(BUF) do {                                             \
        _Pragma("unroll")                                                     \
        for (int i = 0; i < 4; ++i) {                                         \
            const int g = tid + 256 * i, r = g >> 3, gk = g & 7;              \
            const int ad = r * BK + ((gk ^ (r & 7)) * 8);                     \
            s16x8 vh, vl;                                                     \
            _Pragma("unroll")                                                 \
            for (int j = 0; j < 4; ++j) {                                     \
                float v0 = ar[2*i][j];                                        \
                unsigned short h = f2bf(v0);                                  \
                vh[j] = (short)h; vl[j] = (short)f2bf(v0 - bf2f(h));          \
            }                                                                 \
            _Pragma("unroll")                                                 \
            for (int j = 0; j < 4; ++j) {                                     \
                float v0 = ar[2*i+1][j];                                      \
                unsigned short h = f2bf(v0);                                  \
                vh[4+j] = (short)h; vl[4+j] = (short)f2bf(v0 - bf2f(h));      \
            }                                                                 \
            *(s16x8*)&lds[BUF][0][ad] = vh;                                   \
            *(s16x8*)&lds[BUF][1][ad] = vl;                                   \
            *(uint4*)&lds[BUF][2][ad] = brh[i];                               \
            *(uint4*)&lds[BUF][3][ad] = brl[i];                               \
        }                                                                     \
    } while (0)

    #define COMPUTE(BUF) do {                                                 \
        _Pragma("unroll")                                                     \
        for (int kh = 0; kh < 2; ++kh) {                                      \
            s16x8 afh[4], afl[4], bfh[4], bfl[4];                             \
            const int kg = kh * 4 + (lane >> 4);                              \
            _Pragma("unroll")                                                 \
            for (int m = 0; m < 4; ++m) {                                     \
                const int r = wr * 64 + m * 16 + (lane & 15);                 \
                const int ad = r * BK + ((kg ^ (r & 7)) * 8);                 \
                afh[m] = *(const s16x8*)&lds[BUF][0][ad];                     \
                afl[m] = *(const s16x8*)&lds[BUF][1][ad];                     \
            }                                                                 \
            _Pragma("unroll")                                                 \
            for (int n = 0; n < 4; ++n) {                                     \
                const int c = wc * 64 + n * 16 + (lane & 15);                 \
                const int ad = c * BK + ((kg ^ (c & 7)) * 8);                 \
                bfh[n] = *(const s16x8*)&lds[BUF][2][ad];                     \
                bfl[n] = *(const s16x8*)&lds[BUF][3][ad];                     \
            }                                                                 \
            _Pragma("unroll")                                                 \
            for (int m = 0; m < 4; ++m)                                       \
            _Pragma("unroll")                                                 \
            for (int n = 0; n < 4; ++n) {                                     \
                acc[m][n] = MFMA(afh[m], bfh[n], acc[m][n], 0, 0, 0);         \
                acc[m][n] = MFMA(afh[m], bfl[n], acc[m][n], 0, 0, 0);         \
                acc[m][n] = MFMA(afl[m], bfh[n], acc[m][n], 0, 0, 0);         \
            }                                                                 \
        }                                                                     \
    } while (0)

    STAGE_WRITE(0);
    __syncthreads();
    for (int t = 0; t < nt; ++t) {
        const int cur = t & 1;
        if (t + 1 < nt) {
            const int k0 = (t + 1) * BK;
            #pragma unroll
            for (int i = 0; i < 4; ++i) {
                const int g = tid + 256 * i, r = g >> 3, gk = g & 7;
                ar[2*i]   = *(const f32x4*)&Ab[(size_t)r * astride + k0 + gk * 8];
                ar[2*i+1] = *(const f32x4*)&Ab[(size_t)r * astride + k0 + gk * 8 + 4];
                brh[i] = *(const uint4*)&Bph[(size_t)r * bstride + k0 + gk * 8];
                brl[i] = *(const uint4*)&Bpl[(size_t)r * bstride + k0 + gk * 8];
            }
        }
        COMPUTE(cur);
        if (t + 1 < nt) STAGE_WRITE(cur ^ 1);
        __syncthreads();
    }
    #undef STAGE_WRITE
    #undef COMPUTE
}

// ---------------------------------------------------------------------------
// Prep: WT_hi/lo[n][k] = split(W[k][n])
// ---------------------------------------------------------------------------
__global__ __launch_bounds__(256) void wprep_kernel(
    const float* __restrict__ Wm,
    unsigned short* __restrict__ wt_hi, unsigned short* __restrict__ wt_lo)
{
    const int nn = blockIdx.x, k = threadIdx.x;
    const float v = Wm[(size_t)k * HD + nn];
    const unsigned short h = f2bf(v);
    wt_hi[nn * FDIM + k] = h;
    wt_lo[nn * FDIM + k] = f2bf(v - bf2f(h));
}

// ---------------------------------------------------------------------------
// GEMM1: Wh = features @ W. Emits WhT hi/lo [b][col][node] bf16 + e[b][h][n].
// grid (128, 2), 256 threads.
// ---------------------------------------------------------------------------
__global__ __launch_bounds__(256) void gemm1_kernel(
    const float* __restrict__ features,
    const unsigned short* __restrict__ wt_hi,
    const unsigned short* __restrict__ wt_lo,
    unsigned short* __restrict__ WhT_hi,
    unsigned short* __restrict__ WhT_lo,
    float* __restrict__ e_out)
{
    __shared__ unsigned short lds[2][4][128 * BK];

    const int tid = threadIdx.x;
    const int lane = tid & 63;
    const int w = tid >> 6;
    const int wr = w >> 1, wc = w & 1;
    const int row0 = blockIdx.x * 128;     // global node-row (batches concat)
    const int col0 = blockIdx.y * 128;

    f32x4 acc[4][4];
    #pragma unroll
    for (int m = 0; m < 4; ++m)
        #pragma unroll
        for (int n = 0; n < 4; ++n) acc[m][n] = (f32x4)0.f;

    mfma_mainloop(features + (size_t)row0 * FDIM, FDIM,
                  wt_hi + (size_t)col0 * FDIM, wt_lo + (size_t)col0 * FDIM, FDIM,
                  FDIM / BK, lds, tid, lane, wr, wc, acc);

    // ---- e: per-row sum of squares over this wave's 64 cols (one head)
    const int head = blockIdx.y * 2 + wc;
    #pragma unroll
    for (int m = 0; m < 4; ++m)
        #pragma unroll
        for (int r = 0; r < 4; ++r) {
            float p = 0.f;
            #pragma unroll
            for (int n = 0; n < 4; ++n) p += acc[m][n][r] * acc[m][n][r];
            p += __shfl_xor(p, 1, 64);
            p += __shfl_xor(p, 2, 64);
            p += __shfl_xor(p, 4, 64);
            p += __shfl_xor(p, 8, 64);
            if ((lane & 15) == 0) {
                const int row = row0 + wr * 64 + m * 16 + (lane >> 4) * 4 + r;
                e_out[((size_t)((row >> 11) * NH + head)) * NNODE + (row & 2047)] = p;
            }
        }

    // ---- WhT hi/lo via swizzled LDS transpose
    __syncthreads();
    unsigned short* Th = &lds[0][0][0];   // 16384 ushorts (spans slots 0,1)
    unsigned short* Tl = &lds[0][2][0];   // spans slots 2,3
    #pragma unroll
    for (int m = 0; m < 4; ++m)
        #pragma unroll
        for (int n = 0; n < 4; ++n)
            #pragma unroll
            for (int r = 0; r < 4; ++r) {
                const int rr = wr * 64 + m * 16 + (lane >> 4) * 4 + r;
                const int cc = wc * 64 + n * 16 + (lane & 15);
                const int ad = cc * 128 + ((((rr >> 3) ^ (cc & 15))) << 3) + (rr & 7);
                const float v = acc[m][n][r];
                const unsigned short h = f2bf(v);
                Th[ad] = h;
                Tl[ad] = f2bf(v - bf2f(h));
            }
    __syncthreads();
    const int bb = row0 >> 11, kk0 = row0 & 2047;
    #pragma unroll
    for (int i = 0; i < 8; ++i) {
        const int gid = tid + 256 * i;      // 2048 granules of 8 rows
        const int c = gid >> 4, gr = gid & 15;
        const int ad = c * 128 + ((gr ^ (c & 15)) << 3);
        uint4 vh = *(const uint4*)&Th[ad];
        uint4 vl = *(const uint4*)&Tl[ad];
        const size_t o = ((size_t)bb * HD + col0 + c) * NNODE + kk0 + gr * 8;
        *(uint4*)&WhT_hi[o] = vh;
        *(uint4*)&WhT_lo[o] = vl;
    }
}

// ---------------------------------------------------------------------------
// per-(b,h) softmax stats over nodes
// ---------------------------------------------------------------------------
__global__ __launch_bounds__(256) void sm_kernel(
    const float* __restrict__ e, float* __restrict__ ms)
{
    __shared__ float red[8];
    const int bh = blockIdx.x, tid = threadIdx.x;
    const int lane = tid & 63, w = tid >> 6;
    const float* row = e + (size_t)bh * NNODE;
    float mx = -3.0e38f;
    for (int n = tid; n < NNODE; n += 256) mx = fmaxf(mx, row[n]);
    #pragma unroll
    for (int off = 32; off; off >>= 1) mx = fmaxf(mx, __shfl_xor(mx, off, 64));
    if (lane == 0) red[w] = mx;
    __syncthreads();
    mx = fmaxf(fmaxf(red[0], red[1]), fmaxf(red[2], red[3]));
    float s = 0.f;
    for (int n = tid; n < NNODE; n += 256) s += expf(row[n] - mx);
    #pragma unroll
    for (int off = 32; off; off >>= 1) s += __shfl_xor(s, off, 64);
    if (lane == 0) red[4 + w] = s;
    __syncthreads();
    if (tid == 0) {
        ms[bh * 2] = mx;
        ms[bh * 2 + 1] = red[4] + red[5] + red[6] + red[7];
    }
}

__global__ __launch_bounds__(256) void att_kernel(
    const float* __restrict__ e, const float* __restrict__ ms,
    float* __restrict__ attv)
{
    const int i = blockIdx.x * 256 + threadIdx.x;
    const int b = i >> 11, n = i & 2047;
    float a = 0.f;
    #pragma unroll
    for (int h = 0; h < NH; ++h) {
        const int bh = b * NH + h;
        a += expf(e[(size_t)bh * NNODE + n] - ms[bh * 2]) / ms[bh * 2 + 1];
    }
    attv[i] = 0.25f * a;
}

// ---------------------------------------------------------------------------
// GEMM2: out = relu(att[row] * (adj @ Wh) + bias). grid (16, 2, 8).
// ---------------------------------------------------------------------------
__global__ __launch_bounds__(256) void gemm2_kernel(
    const float* __restrict__ adj,
    const unsigned short* __restrict__ WhT_hi,
    const unsigned short* __restrict__ WhT_lo,
    const float* __restrict__ att,
    const float* __restrict__ bias,
    float* __restrict__ out)
{
    __shared__ unsigned short lds[2][4][128 * BK];

    const int tid = threadIdx.x;
    const int lane = tid & 63;
    const int w = tid >> 6;
    const int wr = w >> 1, wc = w & 1;
    const int b = blockIdx.z;
    const int row0 = blockIdx.x * 128, col0 = blockIdx.y * 128;

    f32x4 acc[4][4];
    #pragma unroll
    for (int m = 0; m < 4; ++m)
        #pragma unroll
        for (int n = 0; n < 4; ++n) acc[m][n] = (f32x4)0.f;

    mfma_mainloop(adj + (size_t)b * NNODE * NNODE + (size_t)row0 * NNODE, NNODE,
                  WhT_hi + ((size_t)b * HD + col0) * NNODE,
                  WhT_lo + ((size_t)b * HD + col0) * NNODE, NNODE,
                  NNODE / BK, lds, tid, lane, wr, wc, acc);

    const float* attb = att + (size_t)b * NNODE;
    #pragma unroll
    for (int n = 0; n < 4; ++n) {
        const int c = col0 + wc * 64 + n * 16 + (lane & 15);
        const float bv = bias[c];
        #pragma unroll
        for (int m = 0; m < 4; ++m)
            #pragma unroll
            for (int r = 0; r < 4; ++r) {
                const int row = row0 + wr * 64 + m * 16 + (lane >> 4) * 4 + r;
                const float a = attb[row];
                out[((size_t)b * NNODE + row) * HD + c] =
                    fmaxf(fmaf(acc[m][n][r], a, bv), 0.f);
            }
    }
}

extern "C" void kernel_launch(void* const* d_in, const int* in_sizes, int n_in,
                              void* d_out, int out_size, void* d_ws, size_t ws_size,
                              hipStream_t stream) {
    const float* features = (const float*)d_in[0];
    const float* adj      = (const float*)d_in[1];
    const float* Wm       = (const float*)d_in[2];
    const float* bias     = (const float*)d_in[3];
    float* out = (float*)d_out;

    unsigned short* WhT_hi = (unsigned short*)d_ws;            // 4,194,304
    unsigned short* WhT_lo = WhT_hi + (size_t)BATCH * HD * NNODE;
    unsigned short* wt_hi  = WhT_lo + (size_t)BATCH * HD * NNODE;   // 65536
    unsigned short* wt_lo  = wt_hi + FDIM * HD;
    float* e    = (float*)(wt_lo + FDIM * HD);                 // 65536 floats
    float* ms   = e + (size_t)BATCH * NH * NNODE;              // 64 floats
    float* attv = ms + 64;                                     // 16384 floats

    wprep_kernel<<<HD, 256, 0, stream>>>(Wm, wt_hi, wt_lo);
    gemm1_kernel<<<dim3(MROWS / 128, 2), 256, 0, stream>>>(
        features, wt_hi, wt_lo, WhT_hi, WhT_lo, e);
    sm_kernel<<<BATCH * NH, 256, 0, stream>>>(e, ms);
    att_kernel<<<MROWS / 256, 256, 0, stream>>>(e, ms, attv);
    gemm2_kernel<<<dim3(NNODE / 128, 2, BATCH), 256, 0, stream>>>(
        adj, WhT_hi, WhT_lo, attv, bias, out);
}

// Round 5
// 289.039 us; speedup vs baseline: 1.6918x; 1.1219x over previous
//
#include <hip/hip_runtime.h>
#include <hip/hip_bf16.h>

#define BATCH 8
#define NNODE 2048
#define FDIM 256
#define HD 256
#define NH 4
#define MROWS (BATCH*NNODE)

typedef float f32x4 __attribute__((ext_vector_type(4)));
typedef short s16x8 __attribute__((ext_vector_type(8)));
typedef unsigned short ushort_t;

#define MFMA __builtin_amdgcn_mfma_f32_16x16x32_bf16
#define SCHED0() __builtin_amdgcn_sched_barrier(0)
#define SBAR() __builtin_amdgcn_s_barrier()

// truncation hi/lo split: f = hi + lo + eps, |eps| <= 2^-16 |f|
__device__ __forceinline__ void split2(float f, ushort_t& h, ushort_t& l) {
    unsigned u = __builtin_bit_cast(unsigned, f);
    h = (ushort_t)(u >> 16);
    float fh = __builtin_bit_cast(float, u & 0xffff0000u);
    float lo = f - fh;                       // exact
    l = (ushort_t)(__builtin_bit_cast(unsigned, lo) >> 16);
}

// global -> LDS direct (wave-uniform LDS base + lane*16; per-lane global src)
#define GLOAD16(gp, lp) __builtin_amdgcn_global_load_lds( \
    (const __attribute__((address_space(1))) void*)(gp),  \
    (__attribute__((address_space(3))) void*)(lp), 16, 0, 0)

// ---------------------------------------------------------------------------
// wprep: wt_hi/lo[n][k] = trunc-split(W[k][n])
// ---------------------------------------------------------------------------
__global__ __launch_bounds__(256) void wprep_kernel(
    const float* __restrict__ Wm,
    ushort_t* __restrict__ wt_hi, ushort_t* __restrict__ wt_lo)
{
    const int nn = blockIdx.x, k = threadIdx.x;
    ushort_t h, l;
    split2(Wm[(size_t)k * HD + nn], h, l);
    wt_hi[nn * FDIM + k] = h;
    wt_lo[nn * FDIM + k] = l;
}

// ---------------------------------------------------------------------------
// GEMM1: Wh = features @ W. 64x64 tiles, BK=64, K=256 (4 tiles).
// grid (256, 4); 4 waves 2x2; wave tile 32x32. Emits WhT hi/lo + e.
// ---------------------------------------------------------------------------
__global__ __launch_bounds__(256, 4) void gemm1_kernel(
    const float* __restrict__ features,
    const ushort_t* __restrict__ wt_hi,
    const ushort_t* __restrict__ wt_lo,
    ushort_t* __restrict__ WhT_hi,
    ushort_t* __restrict__ WhT_lo,
    float* __restrict__ e_out)
{
    __shared__ __align__(16) ushort_t Ah[64 * 64];
    __shared__ __align__(16) ushort_t Al[64 * 64];
    __shared__ __align__(16) ushort_t Bh[64 * 64];
    __shared__ __align__(16) ushort_t Bl[64 * 64];
    __shared__ float red[64][2];

    const int tid = threadIdx.x, lane = tid & 63, w = tid >> 6;
    const int wr = w >> 1, wc = w & 1;
    const int row0 = blockIdx.x * 64;     // global row (batches concat)
    const int head = blockIdx.y;
    const int col0 = head * 64;

    const float* Ab = features + (size_t)row0 * FDIM;
    const ushort_t* Bhg = wt_hi + (size_t)col0 * FDIM;
    const ushort_t* Blg = wt_lo + (size_t)col0 * FDIM;

    // staging maps
    const int sr0 = tid >> 3;            // A: rows (i=0: 0..31, i=1: 32..63)
    const int sg8 = tid & 7;             // A: k-granule
    const int bc = (lane >> 3);          // B: row-in-group
    const int bs = lane & 7;             // B: lds slot

    f32x4 ar[4];
    f32x4 acc[2][2];
    #pragma unroll
    for (int m = 0; m < 2; ++m)
        #pragma unroll
        for (int n = 0; n < 2; ++n) acc[m][n] = (f32x4)0.f;

    #define G1_LOADA(K0) do {                                                  \
        _Pragma("unroll")                                                      \
        for (int i = 0; i < 2; ++i) {                                          \
            const int r = sr0 + 32 * i;                                        \
            ar[2*i]   = *(const f32x4*)&Ab[(size_t)r * FDIM + (K0) + sg8 * 8]; \
            ar[2*i+1] = *(const f32x4*)&Ab[(size_t)r * FDIM + (K0) + sg8 * 8 + 4]; \
        }                                                                      \
    } while (0)

    #define G1_STAGEA() do {                                                   \
        _Pragma("unroll")                                                      \
        for (int i = 0; i < 2; ++i) {                                          \
            const int r = sr0 + 32 * i;                                        \
            s16x8 vh, vl; ushort_t hh, ll;                                     \
            _Pragma("unroll")                                                  \
            for (int j = 0; j < 4; ++j) {                                      \
                split2(ar[2*i][j], hh, ll);  vh[j] = (short)hh; vl[j] = (short)ll; \
            }                                                                  \
            _Pragma("unroll")                                                  \
            for (int j = 0; j < 4; ++j) {                                      \
                split2(ar[2*i+1][j], hh, ll); vh[4+j] = (short)hh; vl[4+j] = (short)ll; \
            }                                                                  \
            const int off = r * 64 + ((sg8 ^ (r & 7)) << 3);                   \
            *(s16x8*)&Ah[off] = vh; *(s16x8*)&Al[off] = vl;                    \
        }                                                                      \
    } while (0)

    #define G1_STAGEB(K0) do {                                                 \
        _Pragma("unroll")                                                      \
        for (int qq = 0; qq < 2; ++qq) {                                       \
            const int q = w + qq * 4;                                          \
            const int c = q * 8 + bc;                                          \
            const int g = bs ^ (c & 7);                                        \
            GLOAD16(&Bhg[(size_t)c * FDIM + (K0) + g * 8], &Bh[q * 512]);      \
            GLOAD16(&Blg[(size_t)c * FDIM + (K0) + g * 8], &Bl[q * 512]);      \
        }                                                                      \
    } while (0)

    G1_LOADA(0);
    for (int t = 0; t < 4; ++t) {
        G1_STAGEB(t * 64);
        G1_STAGEA();
        if (t < 3) G1_LOADA((t + 1) * 64);
        if (t < 3) { asm volatile("s_waitcnt lgkmcnt(0) vmcnt(4)" ::: "memory"); }
        else       { asm volatile("s_waitcnt lgkmcnt(0) vmcnt(0)" ::: "memory"); }
        SCHED0(); SBAR(); SCHED0();
        #pragma unroll
        for (int kh = 0; kh < 2; ++kh) {
            const int kg = kh * 4 + (lane >> 4);
            s16x8 afh[2], afl[2], bfh[2], bfl[2];
            #pragma unroll
            for (int m = 0; m < 2; ++m) {
                const int r = wr * 32 + m * 16 + (lane & 15);
                const int off = r * 64 + ((kg ^ (r & 7)) << 3);
                afh[m] = *(const s16x8*)&Ah[off];
                afl[m] = *(const s16x8*)&Al[off];
            }
            #pragma unroll
            for (int n = 0; n < 2; ++n) {
                const int c = wc * 32 + n * 16 + (lane & 15);
                const int off = c * 64 + ((kg ^ (c & 7)) << 3);
                bfh[n] = *(const s16x8*)&Bh[off];
                bfl[n] = *(const s16x8*)&Bl[off];
            }
            #pragma unroll
            for (int m = 0; m < 2; ++m)
                #pragma unroll
                for (int n = 0; n < 2; ++n) {
                    acc[m][n] = MFMA(afh[m], bfh[n], acc[m][n], 0, 0, 0);
                    acc[m][n] = MFMA(afh[m], bfl[n], acc[m][n], 0, 0, 0);
                    acc[m][n] = MFMA(afl[m], bfh[n], acc[m][n], 0, 0, 0);
                }
        }
        SCHED0(); SBAR(); SCHED0();
    }

    // ---- e: row sums of squares (64 cols of this head)
    #pragma unroll
    for (int m = 0; m < 2; ++m)
        #pragma unroll
        for (int j = 0; j < 4; ++j) {
            float p = acc[m][0][j] * acc[m][0][j] + acc[m][1][j] * acc[m][1][j];
            p += __shfl_xor(p, 1, 64);
            p += __shfl_xor(p, 2, 64);
            p += __shfl_xor(p, 4, 64);
            p += __shfl_xor(p, 8, 64);
            if ((lane & 15) == 0)
                red[wr * 32 + m * 16 + (lane >> 4) * 4 + j][wc] = p;
        }

    // ---- WhT transpose via LDS (reuse Ah/Al)
    ushort_t* Th = Ah;   // [64 cols][64 rows] swizzled
    ushort_t* Tl = Al;
    #pragma unroll
    for (int m = 0; m < 2; ++m)
        #pragma unroll
        for (int n = 0; n < 2; ++n)
            #pragma unroll
            for (int j = 0; j < 4; ++j) {
                const int rr = wr * 32 + m * 16 + (lane >> 4) * 4 + j;
                const int cc = wc * 32 + n * 16 + (lane & 15);
                const int ad = cc * 64 + ((((rr >> 3) ^ (cc & 7))) << 3) + (rr & 7);
                ushort_t hh, ll;
                split2(acc[m][n][j], hh, ll);
                Th[ad] = hh; Tl[ad] = ll;
            }
    __syncthreads();

    if (tid < 64) {
        const int rg = row0 + tid;
        e_out[((size_t)((rg >> 11) * NH + head)) * NNODE + (rg & 2047)] =
            red[tid][0] + red[tid][1];
    }
    const int bb = row0 >> 11, node0 = row0 & 2047;
    #pragma unroll
    for (int i = 0; i < 2; ++i) {
        const int gid = tid + 256 * i;       // 512 granules: 64 cols x 8
        const int c = gid >> 3, gr = gid & 7;
        const int ad = c * 64 + ((gr ^ (c & 7)) << 3);
        uint4 vh = *(const uint4*)&Th[ad];
        uint4 vl = *(const uint4*)&Tl[ad];
        const size_t o = ((size_t)bb * HD + col0 + c) * NNODE + node0 + gr * 8;
        *(uint4*)&WhT_hi[o] = vh;
        *(uint4*)&WhT_lo[o] = vl;
    }
}

// ---------------------------------------------------------------------------
// softmax stats + att
// ---------------------------------------------------------------------------
__global__ __launch_bounds__(256) void sm_kernel(
    const float* __restrict__ e, float* __restrict__ ms)
{
    __shared__ float red[8];
    const int bh = blockIdx.x, tid = threadIdx.x;
    const int lane = tid & 63, w = tid >> 6;
    const float* row = e + (size_t)bh * NNODE;
    float mx = -3.0e38f;
    for (int n = tid; n < NNODE; n += 256) mx = fmaxf(mx, row[n]);
    #pragma unroll
    for (int off = 32; off; off >>= 1) mx = fmaxf(mx, __shfl_xor(mx, off, 64));
    if (lane == 0) red[w] = mx;
    __syncthreads();
    mx = fmaxf(fmaxf(red[0], red[1]), fmaxf(red[2], red[3]));
    float s = 0.f;
    for (int n = tid; n < NNODE; n += 256) s += expf(row[n] - mx);
    #pragma unroll
    for (int off = 32; off; off >>= 1) s += __shfl_xor(s, off, 64);
    if (lane == 0) red[4 + w] = s;
    __syncthreads();
    if (tid == 0) {
        ms[bh * 2] = mx;
        ms[bh * 2 + 1] = red[4] + red[5] + red[6] + red[7];
    }
}

__global__ __launch_bounds__(256) void att_kernel(
    const float* __restrict__ e, const float* __restrict__ ms,
    float* __restrict__ attv)
{
    const int i = blockIdx.x * 256 + threadIdx.x;
    const int b = i >> 11, n = i & 2047;
    float a = 0.f;
    #pragma unroll
    for (int h = 0; h < NH; ++h) {
        const int bh = b * NH + h;
        a += expf(e[(size_t)bh * NNODE + n] - ms[bh * 2]) / ms[bh * 2 + 1];
    }
    attv[i] = 0.25f * a;
}

// ---------------------------------------------------------------------------
// GEMM2: out = relu(att[row]*(adj @ Wh) + bias). 128x64 tiles, BK=64.
// grid (16,4,8) = 512 blocks, 2 blocks/CU (64 KB LDS). 4 waves 2x2;
// wave tile 64x32. A reg-staged fp32->split; B dbuf via global_load_lds.
// ---------------------------------------------------------------------------
__global__ __launch_bounds__(256, 2) void gemm2_kernel(
    const float* __restrict__ adj,
    const ushort_t* __restrict__ WhT_hi,
    const ushort_t* __restrict__ WhT_lo,
    const float* __restrict__ att,
    const float* __restrict__ bias,
    float* __restrict__ out)
{
    __shared__ __align__(16) ushort_t Ah[128 * 64];     // 16 KB
    __shared__ __align__(16) ushort_t Al[128 * 64];     // 16 KB
    __shared__ __align__(16) ushort_t Bh[2][64 * 64];   // 2 x 8 KB
    __shared__ __align__(16) ushort_t Bl[2][64 * 64];   // 2 x 8 KB

    const int tid = threadIdx.x, lane = tid & 63, w = tid >> 6;
    const int wr = w >> 1, wc = w & 1;
    const int b = blockIdx.z;
    const int row0 = blockIdx.x * 128, col0 = blockIdx.y * 64;

    const float* Ab = adj + (size_t)b * NNODE * NNODE + (size_t)row0 * NNODE;
    const ushort_t* Bhg = WhT_hi + ((size_t)b * HD + col0) * NNODE;
    const ushort_t* Blg = WhT_lo + ((size_t)b * HD + col0) * NNODE;

    const int sr0 = tid >> 3;            // A rows per i: sr0 + 32*i
    const int sg8 = tid & 7;
    const int bc = lane >> 3, bs = lane & 7;

    f32x4 ar[8];
    f32x4 acc[4][2];
    #pragma unroll
    for (int m = 0; m < 4; ++m)
        #pragma unroll
        for (int n = 0; n < 2; ++n) acc[m][n] = (f32x4)0.f;

    #define G2_LOADA(K0) do {                                                   \
        _Pragma("unroll")                                                       \
        for (int i = 0; i < 4; ++i) {                                           \
            const int r = sr0 + 32 * i;                                         \
            ar[2*i]   = *(const f32x4*)&Ab[(size_t)r * NNODE + (K0) + sg8 * 8]; \
            ar[2*i+1] = *(const f32x4*)&Ab[(size_t)r * NNODE + (K0) + sg8 * 8 + 4]; \
        }                                                                       \
    } while (0)

    #define G2_STAGEA() do {                                                    \
        _Pragma("unroll")                                                       \
        for (int i = 0; i < 4; ++i) {                                           \
            const int r = sr0 + 32 * i;                                         \
            s16x8 vh, vl; ushort_t hh, ll;                                      \
            _Pragma("unroll")                                                   \
            for (int j = 0; j < 4; ++j) {                                       \
                split2(ar[2*i][j], hh, ll);  vh[j] = (short)hh; vl[j] = (short)ll; \
            }                                                                   \
            _Pragma("unroll")                                                   \
            for (int j = 0; j < 4; ++j) {                                       \
                split2(ar[2*i+1][j], hh, ll); vh[4+j] = (short)hh; vl[4+j] = (short)ll; \
            }                                                                   \
            const int off = r * 64 + ((sg8 ^ (r & 7)) << 3);                    \
            *(s16x8*)&Ah[off] = vh; *(s16x8*)&Al[off] = vl;                     \
        }                                                                       \
    } while (0)

    #define G2_STAGEB(BUF, K0) do {                                             \
        _Pragma("unroll")                                                       \
        for (int qq = 0; qq < 2; ++qq) {                                        \
            const int q = w + qq * 4;                                           \
            const int c = q * 8 + bc;                                           \
            const int g = bs ^ (c & 7);                                         \
            GLOAD16(&Bhg[(size_t)c * NNODE + (K0) + g * 8], &Bh[BUF][q * 512]); \
            GLOAD16(&Blg[(size_t)c * NNODE + (K0) + g * 8], &Bl[BUF][q * 512]); \
        }                                                                       \
    } while (0)

    #define G2_COMPUTE(BUF) do {                                                \
        _Pragma("unroll")                                                       \
        for (int kh = 0; kh < 2; ++kh) {                                        \
            const int kg = kh * 4 + (lane >> 4);                                \
            s16x8 afh[4], afl[4], bfh[2], bfl[2];                               \
            _Pragma("unroll")                                                   \
            for (int m = 0; m < 4; ++m) {                                       \
                const int r = wr * 64 + m * 16 + (lane & 15);                   \
                const int off = r * 64 + ((kg ^ (r & 7)) << 3);                 \
                afh[m] = *(const s16x8*)&Ah[off];                               \
                afl[m] = *(const s16x8*)&Al[off];                               \
            }                                                                   \
            _Pragma("unroll")                                                   \
            for (int n = 0; n < 2; ++n) {                                       \
                const int c = wc * 32 + n * 16 + (lane & 15);                   \
                const int off = c * 64 + ((kg ^ (c & 7)) << 3);                 \
                bfh[n] = *(const s16x8*)&Bh[BUF][off];                          \
                bfl[n] = *(const s16x8*)&Bl[BUF][off];                          \
            }                                                                   \
            _Pragma("unroll")                                                   \
            for (int m = 0; m < 4; ++m)                                         \
            _Pragma("unroll")                                                   \
            for (int n = 0; n < 2; ++n) {                                       \
                acc[m][n] = MFMA(afh[m], bfh[n], acc[m][n], 0, 0, 0);           \
                acc[m][n] = MFMA(afh[m], bfl[n], acc[m][n], 0, 0, 0);           \
                acc[m][n] = MFMA(afl[m], bfh[n], acc[m][n], 0, 0, 0);           \
            }                                                                   \
        }                                                                       \
    } while (0)

    // ---- prologue: A(0) staged, B(0)->buf0, A(1) in flight
    G2_LOADA(0);
    G2_STAGEB(0, 0);
    G2_STAGEA();
    G2_LOADA(64);
    asm volatile("s_waitcnt lgkmcnt(0) vmcnt(8)" ::: "memory");
    SCHED0(); SBAR(); SCHED0();

    for (int t = 0; t < 32; ++t) {
        const int cur = t & 1;
        if (t < 31) G2_STAGEB(cur ^ 1, (t + 1) * 64);   // B(t+1) under compute
        G2_COMPUTE(cur);
        if (t < 31) {
            SCHED0(); SBAR(); SCHED0();                  // all done reading A(t)
            G2_STAGEA();                                 // A(t+1) -> LDS
            if (t < 30) {
                G2_LOADA((t + 2) * 64);                  // A(t+2) in flight
                asm volatile("s_waitcnt lgkmcnt(0) vmcnt(8)" ::: "memory");
            } else {
                asm volatile("s_waitcnt lgkmcnt(0) vmcnt(0)" ::: "memory");
            }
            SCHED0(); SBAR(); SCHED0();
        }
    }

    // ---- epilogue
    const float* attb = att + (size_t)b * NNODE;
    #pragma unroll
    for (int n = 0; n < 2; ++n) {
        const int c = col0 + wc * 32 + n * 16 + (lane & 15);
        const float bv = bias[c];
        #pragma unroll
        for (int m = 0; m < 4; ++m)
            #pragma unroll
            for (int j = 0; j < 4; ++j) {
                const int row = row0 + wr * 64 + m * 16 + (lane >> 4) * 4 + j;
                out[((size_t)b * NNODE + row) * HD + c] =
                    fmaxf(fmaf(acc[m][n][j], attb[row], bv), 0.f);
            }
    }
}

extern "C" void kernel_launch(void* const* d_in, const int* in_sizes, int n_in,
                              void* d_out, int out_size, void* d_ws, size_t ws_size,
                              hipStream_t stream) {
    const float* features = (const float*)d_in[0];
    const float* adj      = (const float*)d_in[1];
    const float* Wm       = (const float*)d_in[2];
    const float* bias     = (const float*)d_in[3];
    float* out = (float*)d_out;

    ushort_t* WhT_hi = (ushort_t*)d_ws;                         // 8.39 MB
    ushort_t* WhT_lo = WhT_hi + (size_t)BATCH * HD * NNODE;     // 8.39 MB
    ushort_t* wt_hi  = WhT_lo + (size_t)BATCH * HD * NNODE;
    ushort_t* wt_lo  = wt_hi + FDIM * HD;
    float* e    = (float*)(wt_lo + FDIM * HD);
    float* ms   = e + (size_t)BATCH * NH * NNODE;
    float* attv = ms + 64;

    wprep_kernel<<<HD, 256, 0, stream>>>(Wm, wt_hi, wt_lo);
    gemm1_kernel<<<dim3(MROWS / 64, NH), 256, 0, stream>>>(
        features, wt_hi, wt_lo, WhT_hi, WhT_lo, e);
    sm_kernel<<<BATCH * NH, 256, 0, stream>>>(e, ms);
    att_kernel<<<MROWS / 256, 256, 0, stream>>>(e, ms, attv);
    gemm2_kernel<<<dim3(NNODE / 128, HD / 64, BATCH), 256, 0, stream>>>(
        adj, WhT_hi, WhT_lo, attv, bias, out);
}

// Round 6
// 276.848 us; speedup vs baseline: 1.7663x; 1.0440x over previous
//
#include <hip/hip_runtime.h>
#include <hip/hip_bf16.h>

#define BATCH 8
#define NNODE 2048
#define FDIM 256
#define HD 256
#define NH 4
#define MROWS (BATCH*NNODE)

typedef float f32x4 __attribute__((ext_vector_type(4)));
typedef short s16x8 __attribute__((ext_vector_type(8)));
typedef unsigned short ushort_t;

#define MFMA __builtin_amdgcn_mfma_f32_16x16x32_bf16
#define SCHED0() __builtin_amdgcn_sched_barrier(0)
#define SBAR() __builtin_amdgcn_s_barrier()

// truncation hi/lo split: f = hi + lo + eps, |eps| <= 2^-16 |f|
__device__ __forceinline__ void split2(float f, ushort_t& h, ushort_t& l) {
    unsigned u = __builtin_bit_cast(unsigned, f);
    h = (ushort_t)(u >> 16);
    float fh = __builtin_bit_cast(float, u & 0xffff0000u);
    float lo = f - fh;                       // exact
    l = (ushort_t)(__builtin_bit_cast(unsigned, lo) >> 16);
}

// global -> LDS direct (wave-uniform LDS base + lane*16; per-lane global src)
#define GLOAD16(gp, lp) __builtin_amdgcn_global_load_lds( \
    (const __attribute__((address_space(1))) void*)(gp),  \
    (__attribute__((address_space(3))) void*)(lp), 16, 0, 0)

// ---------------------------------------------------------------------------
// wprep: wt_hi/lo[n][k] = trunc-split(W[k][n])
// ---------------------------------------------------------------------------
__global__ __launch_bounds__(256) void wprep_kernel(
    const float* __restrict__ Wm,
    ushort_t* __restrict__ wt_hi, ushort_t* __restrict__ wt_lo)
{
    const int nn = blockIdx.x, k = threadIdx.x;
    ushort_t h, l;
    split2(Wm[(size_t)k * HD + nn], h, l);
    wt_hi[nn * FDIM + k] = h;
    wt_lo[nn * FDIM + k] = l;
}

// ---------------------------------------------------------------------------
// GEMM1: Wh = features @ W. 64x64 tiles, BK=64, K=256 (4 tiles).
// grid (256, 4); 4 waves 2x2; wave tile 32x32. Emits WhT hi/lo + e.
// (unchanged from R5 — passing, cost bounded; diagnose next round if dominant)
// ---------------------------------------------------------------------------
__global__ __launch_bounds__(256, 4) void gemm1_kernel(
    const float* __restrict__ features,
    const ushort_t* __restrict__ wt_hi,
    const ushort_t* __restrict__ wt_lo,
    ushort_t* __restrict__ WhT_hi,
    ushort_t* __restrict__ WhT_lo,
    float* __restrict__ e_out)
{
    __shared__ __align__(16) ushort_t Ah[64 * 64];
    __shared__ __align__(16) ushort_t Al[64 * 64];
    __shared__ __align__(16) ushort_t Bh[64 * 64];
    __shared__ __align__(16) ushort_t Bl[64 * 64];
    __shared__ float red[64][2];

    const int tid = threadIdx.x, lane = tid & 63, w = tid >> 6;
    const int wr = w >> 1, wc = w & 1;
    const int row0 = blockIdx.x * 64;
    const int head = blockIdx.y;
    const int col0 = head * 64;

    const float* Ab = features + (size_t)row0 * FDIM;
    const ushort_t* Bhg = wt_hi + (size_t)col0 * FDIM;
    const ushort_t* Blg = wt_lo + (size_t)col0 * FDIM;

    const int sr0 = tid >> 3;
    const int sg8 = tid & 7;
    const int bc = (lane >> 3);
    const int bs = lane & 7;

    f32x4 ar[4];
    f32x4 acc[2][2];
    #pragma unroll
    for (int m = 0; m < 2; ++m)
        #pragma unroll
        for (int n = 0; n < 2; ++n) acc[m][n] = (f32x4)0.f;

    #define G1_LOADA(K0) do {                                                  \
        _Pragma("unroll")                                                      \
        for (int i = 0; i < 2; ++i) {                                          \
            const int r = sr0 + 32 * i;                                        \
            ar[2*i]   = *(const f32x4*)&Ab[(size_t)r * FDIM + (K0) + sg8 * 8]; \
            ar[2*i+1] = *(const f32x4*)&Ab[(size_t)r * FDIM + (K0) + sg8 * 8 + 4]; \
        }                                                                      \
    } while (0)

    #define G1_STAGEA() do {                                                   \
        _Pragma("unroll")                                                      \
        for (int i = 0; i < 2; ++i) {                                          \
            const int r = sr0 + 32 * i;                                        \
            s16x8 vh, vl; ushort_t hh, ll;                                     \
            _Pragma("unroll")                                                  \
            for (int j = 0; j < 4; ++j) {                                      \
                split2(ar[2*i][j], hh, ll);  vh[j] = (short)hh; vl[j] = (short)ll; \
            }                                                                  \
            _Pragma("unroll")                                                  \
            for (int j = 0; j < 4; ++j) {                                      \
                split2(ar[2*i+1][j], hh, ll); vh[4+j] = (short)hh; vl[4+j] = (short)ll; \
            }                                                                  \
            const int off = r * 64 + ((sg8 ^ (r & 7)) << 3);                   \
            *(s16x8*)&Ah[off] = vh; *(s16x8*)&Al[off] = vl;                    \
        }                                                                      \
    } while (0)

    #define G1_STAGEB(K0) do {                                                 \
        _Pragma("unroll")                                                      \
        for (int qq = 0; qq < 2; ++qq) {                                       \
            const int q = w + qq * 4;                                          \
            const int c = q * 8 + bc;                                          \
            const int g = bs ^ (c & 7);                                        \
            GLOAD16(&Bhg[(size_t)c * FDIM + (K0) + g * 8], &Bh[q * 512]);      \
            GLOAD16(&Blg[(size_t)c * FDIM + (K0) + g * 8], &Bl[q * 512]);      \
        }                                                                      \
    } while (0)

    G1_LOADA(0);
    for (int t = 0; t < 4; ++t) {
        G1_STAGEB(t * 64);
        G1_STAGEA();
        if (t < 3) G1_LOADA((t + 1) * 64);
        if (t < 3) { asm volatile("s_waitcnt lgkmcnt(0) vmcnt(4)" ::: "memory"); }
        else       { asm volatile("s_waitcnt lgkmcnt(0) vmcnt(0)" ::: "memory"); }
        SCHED0(); SBAR(); SCHED0();
        #pragma unroll
        for (int kh = 0; kh < 2; ++kh) {
            const int kg = kh * 4 + (lane >> 4);
            s16x8 afh[2], afl[2], bfh[2], bfl[2];
            #pragma unroll
            for (int m = 0; m < 2; ++m) {
                const int r = wr * 32 + m * 16 + (lane & 15);
                const int off = r * 64 + ((kg ^ (r & 7)) << 3);
                afh[m] = *(const s16x8*)&Ah[off];
                afl[m] = *(const s16x8*)&Al[off];
            }
            #pragma unroll
            for (int n = 0; n < 2; ++n) {
                const int c = wc * 32 + n * 16 + (lane & 15);
                const int off = c * 64 + ((kg ^ (c & 7)) << 3);
                bfh[n] = *(const s16x8*)&Bh[off];
                bfl[n] = *(const s16x8*)&Bl[off];
            }
            #pragma unroll
            for (int m = 0; m < 2; ++m)
                #pragma unroll
                for (int n = 0; n < 2; ++n) {
                    acc[m][n] = MFMA(afh[m], bfh[n], acc[m][n], 0, 0, 0);
                    acc[m][n] = MFMA(afh[m], bfl[n], acc[m][n], 0, 0, 0);
                    acc[m][n] = MFMA(afl[m], bfh[n], acc[m][n], 0, 0, 0);
                }
        }
        SCHED0(); SBAR(); SCHED0();
    }

    // ---- e: row sums of squares (64 cols of this head)
    #pragma unroll
    for (int m = 0; m < 2; ++m)
        #pragma unroll
        for (int j = 0; j < 4; ++j) {
            float p = acc[m][0][j] * acc[m][0][j] + acc[m][1][j] * acc[m][1][j];
            p += __shfl_xor(p, 1, 64);
            p += __shfl_xor(p, 2, 64);
            p += __shfl_xor(p, 4, 64);
            p += __shfl_xor(p, 8, 64);
            if ((lane & 15) == 0)
                red[wr * 32 + m * 16 + (lane >> 4) * 4 + j][wc] = p;
        }

    // ---- WhT transpose via LDS (reuse Ah/Al)
    __syncthreads();
    ushort_t* Th = Ah;
    ushort_t* Tl = Al;
    #pragma unroll
    for (int m = 0; m < 2; ++m)
        #pragma unroll
        for (int n = 0; n < 2; ++n)
            #pragma unroll
            for (int j = 0; j < 4; ++j) {
                const int rr = wr * 32 + m * 16 + (lane >> 4) * 4 + j;
                const int cc = wc * 32 + n * 16 + (lane & 15);
                const int ad = cc * 64 + ((((rr >> 3) ^ (cc & 7))) << 3) + (rr & 7);
                ushort_t hh, ll;
                split2(acc[m][n][j], hh, ll);
                Th[ad] = hh; Tl[ad] = ll;
            }
    __syncthreads();

    if (tid < 64) {
        const int rg = row0 + tid;
        e_out[((size_t)((rg >> 11) * NH + head)) * NNODE + (rg & 2047)] =
            red[tid][0] + red[tid][1];
    }
    const int bb = row0 >> 11, node0 = row0 & 2047;
    #pragma unroll
    for (int i = 0; i < 2; ++i) {
        const int gid = tid + 256 * i;
        const int c = gid >> 3, gr = gid & 7;
        const int ad = c * 64 + ((gr ^ (c & 7)) << 3);
        uint4 vh = *(const uint4*)&Th[ad];
        uint4 vl = *(const uint4*)&Tl[ad];
        const size_t o = ((size_t)bb * HD + col0 + c) * NNODE + node0 + gr * 8;
        *(uint4*)&WhT_hi[o] = vh;
        *(uint4*)&WhT_lo[o] = vl;
    }
}

// ---------------------------------------------------------------------------
// softmax stats + att
// ---------------------------------------------------------------------------
__global__ __launch_bounds__(256) void sm_kernel(
    const float* __restrict__ e, float* __restrict__ ms)
{
    __shared__ float red[8];
    const int bh = blockIdx.x, tid = threadIdx.x;
    const int lane = tid & 63, w = tid >> 6;
    const float* row = e + (size_t)bh * NNODE;
    float mx = -3.0e38f;
    for (int n = tid; n < NNODE; n += 256) mx = fmaxf(mx, row[n]);
    #pragma unroll
    for (int off = 32; off; off >>= 1) mx = fmaxf(mx, __shfl_xor(mx, off, 64));
    if (lane == 0) red[w] = mx;
    __syncthreads();
    mx = fmaxf(fmaxf(red[0], red[1]), fmaxf(red[2], red[3]));
    float s = 0.f;
    for (int n = tid; n < NNODE; n += 256) s += expf(row[n] - mx);
    #pragma unroll
    for (int off = 32; off; off >>= 1) s += __shfl_xor(s, off, 64);
    if (lane == 0) red[4 + w] = s;
    __syncthreads();
    if (tid == 0) {
        ms[bh * 2] = mx;
        ms[bh * 2 + 1] = red[4] + red[5] + red[6] + red[7];
    }
}

__global__ __launch_bounds__(256) void att_kernel(
    const float* __restrict__ e, const float* __restrict__ ms,
    float* __restrict__ attv)
{
    const int i = blockIdx.x * 256 + threadIdx.x;
    const int b = i >> 11, n = i & 2047;
    float a = 0.f;
    #pragma unroll
    for (int h = 0; h < NH; ++h) {
        const int bh = b * NH + h;
        a += expf(e[(size_t)bh * NNODE + n] - ms[bh * 2]) / ms[bh * 2 + 1];
    }
    attv[i] = 0.25f * a;
}

// ---------------------------------------------------------------------------
// GEMM2: out = relu(att[row]*(adj @ Wh) + bias). 128x64 tiles, BK=64.
// grid (16,4,8) = 512 blocks, 2 blocks/CU (48 KB LDS).
// 4 waves STACKED: wave w owns rows [w*32, w*32+32) x all 64 cols.
// A: per-lane direct global->reg->frag (no LDS, no barrier coupling).
// B: triple-buffered LDS via global_load_lds; ONE barrier per K-tile.
// ---------------------------------------------------------------------------
__global__ __launch_bounds__(256, 2) void gemm2_kernel(
    const float* __restrict__ adj,
    const ushort_t* __restrict__ WhT_hi,
    const ushort_t* __restrict__ WhT_lo,
    const float* __restrict__ att,
    const float* __restrict__ bias,
    float* __restrict__ out)
{
    __shared__ __align__(16) ushort_t Bh[3][64 * 64];   // 3 x 8 KB
    __shared__ __align__(16) ushort_t Bl[3][64 * 64];   // 3 x 8 KB

    const int tid = threadIdx.x, lane = tid & 63, w = tid >> 6;
    const int b = blockIdx.z;
    const int row0 = blockIdx.x * 128, col0 = blockIdx.y * 64;

    const ushort_t* Bhg = WhT_hi + ((size_t)b * HD + col0) * NNODE;
    const ushort_t* Blg = WhT_lo + ((size_t)b * HD + col0) * NNODE;

    // per-lane A pointer: row = row0 + w*32 + (lane&15) (+16 for m=1),
    // k base = (lane>>4)*8  -> exactly the MFMA A-fragment layout
    const float* pA = adj + (size_t)b * NNODE * NNODE
                    + (size_t)(row0 + w * 32 + (lane & 15)) * NNODE
                    + ((lane >> 4) * 8);

    const int bc = lane >> 3, bs = lane & 7;

    f32x4 ar[2][2][2];          // [m][ks][half] : A(t+1) in flight
    s16x8 afh[2][2], afl[2][2]; // A(t) fragments
    f32x4 acc[2][4];
    #pragma unroll
    for (int m = 0; m < 2; ++m)
        #pragma unroll
        for (int n = 0; n < 4; ++n) acc[m][n] = (f32x4)0.f;

    #define G2_LOADA(K0) do {                                                   \
        _Pragma("unroll")                                                       \
        for (int m = 0; m < 2; ++m)                                             \
        _Pragma("unroll")                                                       \
        for (int ks = 0; ks < 2; ++ks) {                                        \
            ar[m][ks][0] = *(const f32x4*)&pA[(size_t)m * 16 * NNODE + (K0) + ks * 32]; \
            ar[m][ks][1] = *(const f32x4*)&pA[(size_t)m * 16 * NNODE + (K0) + ks * 32 + 4]; \
        }                                                                       \
    } while (0)

    #define G2_CONVERT() do {                                                   \
        _Pragma("unroll")                                                       \
        for (int m = 0; m < 2; ++m)                                             \
        _Pragma("unroll")                                                       \
        for (int ks = 0; ks < 2; ++ks) {                                        \
            ushort_t hh, ll;                                                    \
            _Pragma("unroll")                                                   \
            for (int h2 = 0; h2 < 2; ++h2)                                      \
            _Pragma("unroll")                                                   \
            for (int j = 0; j < 4; ++j) {                                       \
                split2(ar[m][ks][h2][j], hh, ll);                               \
                afh[m][ks][h2 * 4 + j] = (short)hh;                             \
                afl[m][ks][h2 * 4 + j] = (short)ll;                             \
            }                                                                   \
        }                                                                       \
    } while (0)

    #define G2_STAGEB(BUF, K0) do {                                             \
        _Pragma("unroll")                                                       \
        for (int qq = 0; qq < 2; ++qq) {                                        \
            const int q = w + qq * 4;                                           \
            const int c = q * 8 + bc;                                           \
            const int g = bs ^ (c & 7);                                         \
            GLOAD16(&Bhg[(size_t)c * NNODE + (K0) + g * 8], &Bh[BUF][q * 512]); \
            GLOAD16(&Blg[(size_t)c * NNODE + (K0) + g * 8], &Bl[BUF][q * 512]); \
        }                                                                       \
    } while (0)

    #define G2_COMPUTE(BHP, BLP) do {                                           \
        _Pragma("unroll")                                                       \
        for (int ks = 0; ks < 2; ++ks) {                                        \
            const int kg = ks * 4 + (lane >> 4);                                \
            s16x8 bfh[4], bfl[4];                                               \
            _Pragma("unroll")                                                   \
            for (int n = 0; n < 4; ++n) {                                       \
                const int c = n * 16 + (lane & 15);                             \
                const int off = c * 64 + ((kg ^ (c & 7)) << 3);                 \
                bfh[n] = *(const s16x8*)&(BHP)[off];                            \
                bfl[n] = *(const s16x8*)&(BLP)[off];                            \
            }                                                                   \
            __builtin_amdgcn_s_setprio(1);                                      \
            _Pragma("unroll")                                                   \
            for (int m = 0; m < 2; ++m)                                         \
            _Pragma("unroll")                                                   \
            for (int n = 0; n < 4; ++n) {                                       \
                acc[m][n] = MFMA(afh[m][ks], bfh[n], acc[m][n], 0, 0, 0);       \
                acc[m][n] = MFMA(afh[m][ks], bfl[n], acc[m][n], 0, 0, 0);       \
                acc[m][n] = MFMA(afl[m][ks], bfh[n], acc[m][n], 0, 0, 0);       \
            }                                                                   \
            __builtin_amdgcn_s_setprio(0);                                      \
        }                                                                       \
    } while (0)

    // prologue: B(0) issued FIRST (older than A(0) -> any A-wait drains it)
    G2_STAGEB(0, 0);
    G2_LOADA(0);

    int cur = 0;
    for (int t = 0; t < 32; ++t) {
        const int nxt = (cur == 2) ? 0 : cur + 1;
        if (t < 31) G2_STAGEB(nxt, (t + 1) * 64);
        G2_CONVERT();                      // consumes A(t); implicit wait drains B(t) too
        if (t < 31) G2_LOADA((t + 1) * 64);
        // hard guarantee: own B(t) landed before the barrier releases readers.
        // outstanding newest = B(t+1):4 + A(t+1):8 = 12, so vmcnt(12) drains B(t)
        // wherever the compiler scheduled the convert.
        asm volatile("s_waitcnt vmcnt(12)" ::: "memory");
        SCHED0(); SBAR(); SCHED0();
        {
            const ushort_t* bhp = &Bh[cur][0];
            const ushort_t* blp = &Bl[cur][0];
            G2_COMPUTE(bhp, blp);
        }
        cur = nxt;
        // no trailing barrier: triple-buffer + <=1-iter wave skew keeps
        // writer buf (t+2)%3 disjoint from reader bufs t%3 and (t+1)%3.
    }

    // epilogue
    const float* attb = att + (size_t)b * NNODE;
    #pragma unroll
    for (int n = 0; n < 4; ++n) {
        const int c = col0 + n * 16 + (lane & 15);
        const float bv = bias[c];
        #pragma unroll
        for (int m = 0; m < 2; ++m)
            #pragma unroll
            for (int j = 0; j < 4; ++j) {
                const int row = row0 + w * 32 + m * 16 + (lane >> 4) * 4 + j;
                out[((size_t)b * NNODE + row) * HD + c] =
                    fmaxf(fmaf(acc[m][n][j], attb[row], bv), 0.f);
            }
    }
}

extern "C" void kernel_launch(void* const* d_in, const int* in_sizes, int n_in,
                              void* d_out, int out_size, void* d_ws, size_t ws_size,
                              hipStream_t stream) {
    const float* features = (const float*)d_in[0];
    const float* adj      = (const float*)d_in[1];
    const float* Wm       = (const float*)d_in[2];
    const float* bias     = (const float*)d_in[3];
    float* out = (float*)d_out;

    ushort_t* WhT_hi = (ushort_t*)d_ws;
    ushort_t* WhT_lo = WhT_hi + (size_t)BATCH * HD * NNODE;
    ushort_t* wt_hi  = WhT_lo + (size_t)BATCH * HD * NNODE;
    ushort_t* wt_lo  = wt_hi + FDIM * HD;
    float* e    = (float*)(wt_lo + FDIM * HD);
    float* ms   = e + (size_t)BATCH * NH * NNODE;
    float* attv = ms + 64;

    wprep_kernel<<<HD, 256, 0, stream>>>(Wm, wt_hi, wt_lo);
    gemm1_kernel<<<dim3(MROWS / 64, NH), 256, 0, stream>>>(
        features, wt_hi, wt_lo, WhT_hi, WhT_lo, e);
    sm_kernel<<<BATCH * NH, 256, 0, stream>>>(e, ms);
    att_kernel<<<MROWS / 256, 256, 0, stream>>>(e, ms, attv);
    gemm2_kernel<<<dim3(NNODE / 128, HD / 64, BATCH), 256, 0, stream>>>(
        adj, WhT_hi, WhT_lo, attv, bias, out);
}